// Round 6
// baseline (21.262 us; speedup 1.0000x reference)
//
#include <hip/hip_runtime.h>

#define V 10
#define L 45            // V*(V-1)/2
#define NCOEF 14
#define NSAMP 65536
#define BS 16           // samples per block
#define NTHR 128        // 2 waves
#define LAMP 46         // padded lam row stride

typedef float v4f __attribute__((ext_vector_type(4)));

__global__ __launch_bounds__(NTHR, 8) void decor_fused(
    const float* __restrict__ x, const float* __restrict__ log_d,
    const float* __restrict__ params,
    float* __restrict__ out, float* __restrict__ Mout, float* __restrict__ logd_out,
    float* __restrict__ scal)
{
    __shared__ float ps[NCOEF * L];      // 2.52 KB  params staged in LDS
    __shared__ float xs[BS * V];         // 640 B
    __shared__ float lam[BS * LAMP];     // 2.94 KB

    const int tid = threadIdx.x;
    const int n0  = blockIdx.x * BS;

    // ---- stage params + x tile into LDS (coalesced); log_d passthrough ----
    for (int idx = tid; idx < NCOEF * L; idx += NTHR)
        ps[idx] = params[idx];
    const v4f* x4 = (const v4f*)(x + (size_t)n0 * V);
    for (int idx = tid; idx < BS * V / 4; idx += NTHR)
        ((v4f*)xs)[idx] = __builtin_nontemporal_load(&x4[idx]);
    const v4f* ld4  = (const v4f*)(log_d + (size_t)n0 * V);
    v4f*       ldo4 = (v4f*)(logd_out + (size_t)n0 * V);
    for (int idx = tid; idx < BS * V / 4; idx += NTHR)
        __builtin_nontemporal_store(__builtin_nontemporal_load(&ld4[idx]), &ldo4[idx]);

    __syncthreads();

    // ---- fused M compute + float4 store; lambda LDS side-write for matvec ----
    // uniform knots, spacing d = 10/11; u = (x+5)/d + 3
    const float inv_d = 1.1f;
    const float c16   = 1.0f / 6.0f;
    v4f* M4 = (v4f*)(Mout + (size_t)n0 * V * V);
    for (int idx = tid; idx < BS * 25; idx += NTHR) {
        int nl = idx / 25;
        int q  = idx - nl * 25;
        int e  = q * 4;
        v4f v;
        #pragma unroll
        for (int t = 0; t < 4; ++t) {
            int ee = e + t;
            int i  = (ee * 205) >> 11;         // ee/10 for ee<100
            int j  = ee - 10 * i;
            float val;
            if (j > i)       val = 0.0f;
            else if (j == i) val = 1.0f;
            else {
                float xv = xs[nl * V + j];
                xv = fminf(fmaxf(xv, -5.0f), 5.0f);
                float u  = (xv + 5.0f) * inv_d + 3.0f;
                int   ii = (int)floorf(u);
                ii = max(3, min(ii, 14));      // ref indicator: x=+5 lands in [t14,t15)
                float f  = u - (float)ii;
                float omf = 1.0f - f;
                float f2 = f * f, f3 = f2 * f;
                float N0 = omf * omf * omf * c16;
                float N1 = (3.0f * f3 - 6.0f * f2 + 4.0f) * c16;
                float N2 = (-3.0f * f3 + 3.0f * f2 + 3.0f * f + 1.0f) * c16;
                float N3 = f3 * c16;           // == 0 when ii==14
                int l  = (i * (i - 1)) / 2 + j;
                int k0 = ii - 3;
                int k3 = min(k0 + 3, NCOEF - 1);  // B_14 dropped by ref; N3==0 there
                val = N0 * ps[(k0    ) * L + l]
                    + N1 * ps[(k0 + 1) * L + l]
                    + N2 * ps[(k0 + 2) * L + l]
                    + N3 * ps[(k3    ) * L + l];
                lam[nl * LAMP + l] = val;
            }
            v[t] = val;
        }
        __builtin_nontemporal_store(v, &M4[idx]);
    }
    __syncthreads();

    // ---- out = M @ x (strict-lower + identity), direct coalesced stores ----
    for (int idx = tid; idx < BS * V; idx += NTHR) {
        int nl = idx / V;
        int i  = idx - nl * V;
        float acc = xs[idx];
        const float* lr = &lam[nl * LAMP + (i * (i - 1)) / 2];
        for (int j = 0; j < i; ++j)
            acc += lr[j] * xs[nl * V + j];
        __builtin_nontemporal_store(acc, &out[(size_t)n0 * V + idx]);
    }

    // ---- ridge scalars: one wave of block 0, params from LDS ----
    if (blockIdx.x == 0 && tid < 64) {
        float s_par = 0.f, s_fir = 0.f, s_sec = 0.f;
        for (int idx = tid; idx < NCOEF * L; idx += 64) {
            int k = idx / L;
            float p0 = ps[idx];
            s_par += p0 * p0;
            if (k + 1 < NCOEF) {
                float p1 = ps[idx + L];
                float d1 = p1 - p0;
                s_fir += d1 * d1;
                if (k + 2 < NCOEF) {
                    float p2 = ps[idx + 2 * L];
                    float d2 = p2 - 2.f * p1 + p0;
                    s_sec += d2 * d2;
                }
            }
        }
        for (int off = 32; off; off >>= 1) {
            s_sec += __shfl_down(s_sec, off);
            s_fir += __shfl_down(s_fir, off);
            s_par += __shfl_down(s_par, off);
        }
        if (tid == 0) { scal[0] = s_sec; scal[1] = s_fir; scal[2] = s_par; }
    }
}

extern "C" void kernel_launch(void* const* d_in, const int* in_sizes, int n_in,
                              void* d_out, int out_size, void* d_ws, size_t ws_size,
                              hipStream_t stream) {
    const float* x      = (const float*)d_in[0];
    const float* log_d  = (const float*)d_in[1];
    const float* params = (const float*)d_in[2];

    float* out      = (float*)d_out;                       // [N, V]
    float* M        = out + (size_t)NSAMP * V;             // [N, V, V]
    float* logd_out = M + (size_t)NSAMP * V * V;           // [N, V]
    float* scal     = logd_out + (size_t)NSAMP * V;        // sec, fir, par

    decor_fused<<<NSAMP / BS, NTHR, 0, stream>>>(x, log_d, params, out, M, logd_out, scal);
}

// Round 7
// 19.712 us; speedup vs baseline: 1.0787x; 1.0787x over previous
//
#include <hip/hip_runtime.h>

#define V 10
#define L 45            // V*(V-1)/2
#define NCOEF 14
#define NSAMP 65536
#define BS 64           // samples per block (4 waves x 16)
#define SPW 16          // samples per wave
#define NTHR 256
#define LAMP 46         // padded lam row stride

typedef float v4f __attribute__((ext_vector_type(4)));

// col index j for pair l (tril_indices(V, k=-1) row-major order)
__constant__ unsigned char c_col[L] = {
    0,
    0,1,
    0,1,2,
    0,1,2,3,
    0,1,2,3,4,
    0,1,2,3,4,5,
    0,1,2,3,4,5,6,
    0,1,2,3,4,5,6,7,
    0,1,2,3,4,5,6,7,8
};

__global__ __launch_bounds__(NTHR) void decor_fused(
    const float* __restrict__ x, const float* __restrict__ log_d,
    const float* __restrict__ params,
    float* __restrict__ out, float* __restrict__ Mout, float* __restrict__ logd_out,
    float* __restrict__ scal)
{
    __shared__ float ps[NCOEF * L];          // 2.52 KB, block-shared (1 barrier)
    __shared__ unsigned char cols[64];
    __shared__ float xs[4][SPW * V];         // per-wave, 640 B each
    __shared__ float lam[4][SPW * LAMP];     // per-wave, 2.94 KB each

    const int tid  = threadIdx.x;
    const int w    = tid >> 6;
    const int lane = tid & 63;
    const size_t nw = (size_t)blockIdx.x * BS + w * SPW;   // first sample of this wave

    // ---- block-shared staging: params + col table (coalesced) ----
    for (int idx = tid; idx < NCOEF * L; idx += NTHR)
        ps[idx] = params[idx];
    if (tid < L) cols[tid] = c_col[tid];

    // ---- per-wave x stage + log_d passthrough (no cross-wave deps) ----
    const v4f* x4w = (const v4f*)(x + nw * V);
    if (lane < SPW * V / 4)
        ((v4f*)xs[w])[lane] = __builtin_nontemporal_load(&x4w[lane]);
    const v4f* ld4w  = (const v4f*)(log_d + nw * V);
    v4f*       ldo4w = (v4f*)(logd_out + nw * V);
    if (lane < SPW * V / 4)
        __builtin_nontemporal_store(__builtin_nontemporal_load(&ld4w[lane]), &ldo4w[lane]);

    __syncthreads();   // covers ps/cols only; xs/lam are wave-local after this

    // ---- lambdas: SPW*L = 720 evals per wave, params gathered from LDS ----
    // uniform knots, spacing d = 10/11; u = (x+5)/d + 3
    const float inv_d = 1.1f;
    const float c16   = 1.0f / 6.0f;
    float* lamw = lam[w];
    const float* xw = xs[w];
    for (int e = lane; e < SPW * L; e += 64) {
        int nl = e / L;
        int l  = e - nl * L;
        float xv = xw[nl * V + cols[l]];
        xv = fminf(fmaxf(xv, -5.0f), 5.0f);
        float u  = (xv + 5.0f) * inv_d + 3.0f;
        int   ii = (int)floorf(u);
        ii = max(3, min(ii, 14));          // ref indicator: x=+5 lands in [t14,t15)
        float f  = u - (float)ii;
        float omf = 1.0f - f;
        float f2 = f * f, f3 = f2 * f;
        float N0 = omf * omf * omf * c16;
        float N1 = (3.0f * f3 - 6.0f * f2 + 4.0f) * c16;
        float N2 = (-3.0f * f3 + 3.0f * f2 + 3.0f * f + 1.0f) * c16;
        float N3 = f3 * c16;               // == 0 when ii==14
        int k0 = ii - 3;
        int k3 = min(k0 + 3, NCOEF - 1);   // B_14 dropped by ref; N3==0 there
        lamw[nl * LAMP + l] =
              N0 * ps[(k0    ) * L + l]
            + N1 * ps[(k0 + 1) * L + l]
            + N2 * ps[(k0 + 2) * L + l]
            + N3 * ps[(k3    ) * L + l];
    }

    // ---- assemble + store M (float4, nt), wave-local lam (lgkmcnt orders) ----
    v4f* M4w = (v4f*)(Mout + nw * V * V);
    for (int q = lane; q < SPW * 25; q += 64) {
        int nl = q / 25;
        int qq = q - nl * 25;
        int e0 = qq * 4;
        const float* lr = &lamw[nl * LAMP];
        v4f v;
        #pragma unroll
        for (int t = 0; t < 4; ++t) {
            int ee = e0 + t;
            int i  = (ee * 205) >> 11;     // ee/10 for ee<100
            int j  = ee - 10 * i;
            float val;
            if (j > i)       val = 0.0f;
            else if (j == i) val = 1.0f;
            else             val = lr[(i * (i - 1)) / 2 + j];
            v[t] = val;
        }
        __builtin_nontemporal_store(v, &M4w[q]);
    }

    // ---- out = M @ x (strict-lower + identity), direct coalesced stores ----
    for (int o = lane; o < SPW * V; o += 64) {
        int nl = o / V;
        int i  = o - nl * V;
        float acc = xw[o];
        const float* lr = &lamw[nl * LAMP + (i * (i - 1)) / 2];
        for (int j = 0; j < i; ++j)
            acc += lr[j] * xw[nl * V + j];
        __builtin_nontemporal_store(acc, &out[nw * V + o]);
    }

    // ---- ridge scalars: wave 3 of block 0, params from LDS ----
    if (blockIdx.x == 0 && w == 3) {
        float s_par = 0.f, s_fir = 0.f, s_sec = 0.f;
        for (int idx = lane; idx < NCOEF * L; idx += 64) {
            int k = idx / L;
            float p0 = ps[idx];
            s_par += p0 * p0;
            if (k + 1 < NCOEF) {
                float p1 = ps[idx + L];
                float d1 = p1 - p0;
                s_fir += d1 * d1;
                if (k + 2 < NCOEF) {
                    float p2 = ps[idx + 2 * L];
                    float d2 = p2 - 2.f * p1 + p0;
                    s_sec += d2 * d2;
                }
            }
        }
        for (int off = 32; off; off >>= 1) {
            s_sec += __shfl_down(s_sec, off);
            s_fir += __shfl_down(s_fir, off);
            s_par += __shfl_down(s_par, off);
        }
        if (lane == 0) { scal[0] = s_sec; scal[1] = s_fir; scal[2] = s_par; }
    }
}

extern "C" void kernel_launch(void* const* d_in, const int* in_sizes, int n_in,
                              void* d_out, int out_size, void* d_ws, size_t ws_size,
                              hipStream_t stream) {
    const float* x      = (const float*)d_in[0];
    const float* log_d  = (const float*)d_in[1];
    const float* params = (const float*)d_in[2];

    float* out      = (float*)d_out;                       // [N, V]
    float* M        = out + (size_t)NSAMP * V;             // [N, V, V]
    float* logd_out = M + (size_t)NSAMP * V * V;           // [N, V]
    float* scal     = logd_out + (size_t)NSAMP * V;        // sec, fir, par

    decor_fused<<<NSAMP / BS, NTHR, 0, stream>>>(x, log_d, params, out, M, logd_out, scal);
}